// Round 2
// 317.479 us; speedup vs baseline: 1.1545x; 1.1545x over previous
//
#include <hip/hip_runtime.h>

// DeepFM: B=16384, D=1024, L=4.
// GEMM ported to the 256x256 8-phase counted-vmcnt template (T2+T3+T4+T5):
//   BM=BN=256, BK=64, 512 thr (8 waves, 2Mx4N), per-wave out 128x64.
//   LDS 128 KiB: A/B x dbuf x half(128x64 bf16). 1 block/CU (grid=256=CUs).
//   Swizzle: LDS[row][chunk] holds global[row][chunk ^ (row&7)] (16B chunks);
//   applied via inverse-swizzled GLOBAL source (global_load_lds writes linear)
//   and swizzled ds_read offsets.
//   vmcnt(4) only at phases 4/8 (drain to 0 only in last iteration).

#define DDIM 1024
#define BROWS 16384
#define NIT 8   // K / 128

typedef __attribute__((ext_vector_type(8))) short s8v;   // 8 bf16
typedef __attribute__((ext_vector_type(4))) float f4v;   // 4 fp32

__device__ __forceinline__ unsigned short f2bf(float f) {
    unsigned int u = __float_as_uint(f);
    u += 0x7fffu + ((u >> 16) & 1u);   // round-to-nearest-even
    return (unsigned short)(u >> 16);
}
__device__ __forceinline__ float bf2f(unsigned short u) {
    return __uint_as_float(((unsigned int)u) << 16);
}
__device__ __forceinline__ void gld16(const void* g, void* l) {
    __builtin_amdgcn_global_load_lds(
        (const __attribute__((address_space(1))) unsigned int*)g,
        (__attribute__((address_space(3))) unsigned int*)l, 16, 0, 0);
}

// -------- fused prep: blocks [0,16384) x rows; [16384, 17664) weights ----
__global__ __launch_bounds__(256) void prep_cvt_kernel(
    const float* __restrict__ x,  const float* __restrict__ Ws,
    const float* __restrict__ Wo, unsigned short* __restrict__ xb,
    unsigned short* __restrict__ wb, float* __restrict__ rowsum)
{
    const int t = threadIdx.x;
    if (blockIdx.x < BROWS) {
        const int row = blockIdx.x;
        const float4 v = *(const float4*)(x + (size_t)row * DDIM + t * 4);
        ushort4 o;
        o.x = f2bf(v.x); o.y = f2bf(v.y); o.z = f2bf(v.z); o.w = f2bf(v.w);
        *(ushort4*)(xb + (size_t)row * DDIM + t * 4) = o;
        float s = v.x + v.y + v.z + v.w;
        #pragma unroll
        for (int off = 32; off > 0; off >>= 1) s += __shfl_down(s, off, 64);
        __shared__ float red[4];
        const int wave = t >> 6, lane = t & 63;
        if (lane == 0) red[wave] = s;
        __syncthreads();
        if (t == 0) rowsum[row] = red[0] + red[1] + red[2] + red[3];
    } else {
        const int base = (blockIdx.x - BROWS) * 1024;
        #pragma unroll
        for (int j = 0; j < 4; ++j) {
            const int idx = base + j * 256 + t;
            const float4 v = (idx < 4 * 262144) ? ((const float4*)Ws)[idx]
                                                : ((const float4*)Wo)[idx - 4 * 262144];
            ushort4 o;
            o.x = f2bf(v.x); o.y = f2bf(v.y); o.z = f2bf(v.z); o.w = f2bf(v.w);
            ((ushort4*)wb)[idx] = o;
        }
    }
}

// ---------------- GEMM: C = A(MxK) @ Bw(NxK)^T + bias --------------------
#define MF(a, b, c) __builtin_amdgcn_mfma_f32_16x16x32_bf16(a, b, c, 0, 0, 0)
#define BAR()   __builtin_amdgcn_s_barrier()
#define LGKM0() asm volatile("s_waitcnt lgkmcnt(0)" ::: "memory")
#define VMC(n)  asm volatile("s_waitcnt vmcnt(" #n ")" ::: "memory")

// byte offset within one 128x64-bf16 half-tile, with 16B-chunk XOR swizzle
#define SWOFF(lr, cc) ((lr) * 128 + ((((cc) ^ ((lr) & 7))) << 4))

#define SH(src, dst) {                                              \
    gld16((src) + soff,                   (char*)(dst) + t * 16);   \
    gld16((src) + soff + (size_t)64 * K,  (char*)(dst) + t * 16 + 8192); }

#define READ_A(P, m0) {                                                               \
    af[0][0] = *(const s8v*)((const char*)(P) + SWOFF((m0) * 16 + mrow,      quad));      \
    af[0][1] = *(const s8v*)((const char*)(P) + SWOFF((m0) * 16 + mrow,      4 + quad));  \
    af[1][0] = *(const s8v*)((const char*)(P) + SWOFF((m0) * 16 + 16 + mrow, quad));      \
    af[1][1] = *(const s8v*)((const char*)(P) + SWOFF((m0) * 16 + 16 + mrow, 4 + quad)); }

#define READ_B(P) {                                                                   \
    bfr[0][0] = *(const s8v*)((const char*)(P) + SWOFF(bl + mrow,      quad));            \
    bfr[0][1] = *(const s8v*)((const char*)(P) + SWOFF(bl + mrow,      4 + quad));        \
    bfr[1][0] = *(const s8v*)((const char*)(P) + SWOFF(bl + 16 + mrow, quad));            \
    bfr[1][1] = *(const s8v*)((const char*)(P) + SWOFF(bl + 16 + mrow, 4 + quad));        \
    bfr[2][0] = *(const s8v*)((const char*)(P) + SWOFF(bl + 32 + mrow, quad));            \
    bfr[2][1] = *(const s8v*)((const char*)(P) + SWOFF(bl + 32 + mrow, 4 + quad));        \
    bfr[3][0] = *(const s8v*)((const char*)(P) + SWOFF(bl + 48 + mrow, quad));            \
    bfr[3][1] = *(const s8v*)((const char*)(P) + SWOFF(bl + 48 + mrow, 4 + quad)); }

#define MMA8(m0, s) {                                              \
    acc[m0][0]       = MF(af[0][s], bfr[0][s], acc[m0][0]);        \
    acc[m0][1]       = MF(af[0][s], bfr[1][s], acc[m0][1]);        \
    acc[m0][2]       = MF(af[0][s], bfr[2][s], acc[m0][2]);        \
    acc[m0][3]       = MF(af[0][s], bfr[3][s], acc[m0][3]);        \
    acc[(m0) + 1][0] = MF(af[1][s], bfr[0][s], acc[(m0) + 1][0]);  \
    acc[(m0) + 1][1] = MF(af[1][s], bfr[1][s], acc[(m0) + 1][1]);  \
    acc[(m0) + 1][2] = MF(af[1][s], bfr[2][s], acc[(m0) + 1][2]);  \
    acc[(m0) + 1][3] = MF(af[1][s], bfr[3][s], acc[(m0) + 1][3]); }

#define MMA16(m0) { __builtin_amdgcn_s_setprio(1); MMA8(m0, 0) MMA8(m0, 1) \
                    __builtin_amdgcn_s_setprio(0); }

// MODE 0: out bf16 = relu(z)
// MODE 1: out bf16 = 0.5*(relu(z) + relu(xb*rowsum))   (layer 4 fusion)
// MODE 2: out fp32 = z                                  (final layer)
template <int MODE>
__global__ __launch_bounds__(512, 2) void gemm256(
    const unsigned short* __restrict__ A,
    const unsigned short* __restrict__ Bw,
    const float* __restrict__ bias,
    void* __restrict__ out,
    const unsigned short* __restrict__ xb,
    const float* __restrict__ rowsum)
{
    constexpr int K = DDIM, N = DDIM;
    // [A=0/B=1][buf][half][128*64] bf16 = 128 KiB
    __shared__ unsigned short smem[2][2][2][128 * 64];

    const int t = threadIdx.x;            // 0..511
    const int lane = t & 63;
    const int wid  = t >> 6;              // 0..7
    const int wr   = wid >> 2;            // 0..1  (M half)
    const int wc   = wid & 3;             // 0..3  (N quarter)
    const int mrow = lane & 15;
    const int quad = lane >> 4;
    const int rowBase = blockIdx.x * 256;
    const int colBase = blockIdx.y * 256;

    const unsigned short* const Ab0 = A  + (size_t)rowBase * K;
    const unsigned short* const Ab1 = Ab0 + (size_t)128 * K;
    const unsigned short* const Bb0 = Bw + (size_t)colBase * K;
    const unsigned short* const Bb1 = Bb0 + (size_t)128 * K;

    // staging: thread t covers row t>>3 (+64 for 2nd load), 16B chunk t&7.
    // inverse-swizzled global source so linear LDS dest ends up swizzled.
    const int srow = t >> 3;
    const size_t soff = (size_t)srow * K + (size_t)(((t & 7) ^ (srow & 7)) * 8);

    unsigned short* const a00 = &smem[0][0][0][0];
    unsigned short* const a01 = &smem[0][0][1][0];
    unsigned short* const a10 = &smem[0][1][0][0];
    unsigned short* const a11 = &smem[0][1][1][0];
    unsigned short* const b00 = &smem[1][0][0][0];
    unsigned short* const b01 = &smem[1][0][1][0];
    unsigned short* const b10 = &smem[1][1][0][0];
    unsigned short* const b11 = &smem[1][1][1][0];

    // per-wave read bases: wave's A rows live entirely in half wr;
    // wave's B cols live in half wc>>1 at local row base bl.
    const unsigned short* const aR0 = wr ? a01 : a00;       // buf0
    const unsigned short* const aR1 = wr ? a11 : a10;       // buf1
    const unsigned short* const bR0 = (wc >> 1) ? b01 : b00;
    const unsigned short* const bR1 = (wc >> 1) ? b11 : b10;
    const int bl = (wc & 1) * 64;

    f4v acc[8][4] = {};
    s8v af[2][2], bfr[4][2];

    // ---- prologue: A(0), B(0), B(1); wait A0/B0, let B1 fly --------------
    SH(Ab0,      a00); SH(Ab1,      a01);
    SH(Bb0,      b00); SH(Bb1,      b01);
    SH(Bb0 + 64, b10); SH(Bb1 + 64, b11);
    VMC(4);
    BAR();

    #pragma unroll 1
    for (int it = 0; it < NIT; ++it) {
        const int ka = it * 128, kb = ka + 64;
        const bool more = it < NIT - 1;

        // ======== tile a = 2it (buf0), phases 1-4 ========
        // ph1: all B-frags + A mi{0,1}; stage A(b) half0
        READ_B(bR0); READ_A(aR0, 0);
        SH(Ab0 + kb, a10);
        BAR(); LGKM0(); MMA16(0); BAR();
        // ph2: A mi{2,3}; stage A(b) half1
        READ_A(aR0, 2);
        SH(Ab1 + kb, a11);
        BAR(); LGKM0(); MMA16(2); BAR();
        // ph3: A mi{4,5}; stage B(a+2) half0
        READ_A(aR0, 4);
        if (more) SH(Bb0 + ka + 128, b00);
        BAR(); LGKM0(); MMA16(4); BAR();
        // ph4: A mi{6,7}; stage B(a+2) half1; checkpoint: A(b),B(b) landed
        READ_A(aR0, 6);
        if (more) SH(Bb1 + ka + 128, b01);
        BAR(); LGKM0(); MMA16(6);
        if (more) { VMC(4); } else { VMC(0); }
        BAR();

        // ======== tile b = 2it+1 (buf1), phases 5-8 ========
        // ph5: all B-frags + A mi{0,1}; stage A(a+2) half0
        READ_B(bR1); READ_A(aR1, 0);
        if (more) SH(Ab0 + ka + 128, a00);
        BAR(); LGKM0(); MMA16(0); BAR();
        // ph6: A mi{2,3}; stage A(a+2) half1
        READ_A(aR1, 2);
        if (more) SH(Ab1 + ka + 128, a01);
        BAR(); LGKM0(); MMA16(2); BAR();
        // ph7: A mi{4,5}; stage B(b+2) half0
        READ_A(aR1, 4);
        if (more) SH(Bb0 + kb + 128, b10);
        BAR(); LGKM0(); MMA16(4); BAR();
        // ph8: A mi{6,7}; stage B(b+2) half1; checkpoint: B(a+2),A(a+2) landed
        READ_A(aR1, 6);
        if (more) SH(Bb1 + kb + 128, b11);
        BAR(); LGKM0(); MMA16(6);
        if (more) { VMC(4); }
        BAR();
    }

    // ---- epilogue. C/D layout: col = lane&15, row = quad*4 + reg ---------
    if (MODE == 2) {
        float* sCf = (float*)smem;                 // 128x256 fp32 = 128 KiB
        float* o = (float*)out;
        #pragma unroll 1
        for (int half = 0; half < 2; ++half) {
            __syncthreads();
            if (wr == half) {
                #pragma unroll
                for (int ni = 0; ni < 4; ++ni) {
                    const int n = wc * 64 + ni * 16 + mrow;
                    const float bv = bias[colBase + n];
                    #pragma unroll
                    for (int mi = 0; mi < 8; ++mi)
                        #pragma unroll
                        for (int r = 0; r < 4; ++r)
                            sCf[(mi * 16 + quad * 4 + r) * 256 + n] = acc[mi][ni][r] + bv;
                }
            }
            __syncthreads();
            #pragma unroll
            for (int p = 0; p < 16; ++p) {
                const int idx = t + p * 512;       // float4 chunk 0..8191
                const int row = idx >> 6, ch = idx & 63;
                const float4 v = ((const float4*)sCf)[idx];
                *(float4*)(o + (size_t)(rowBase + half * 128 + row) * N + colBase + ch * 4) = v;
            }
        }
    } else {
        __syncthreads();
        unsigned short* sC = (unsigned short*)smem;  // 256x256 bf16 = 128 KiB
        #pragma unroll
        for (int ni = 0; ni < 4; ++ni) {
            const int n = wc * 64 + ni * 16 + mrow;
            const float bv = bias[colBase + n];
            #pragma unroll
            for (int mi = 0; mi < 8; ++mi)
                #pragma unroll
                for (int r = 0; r < 4; ++r) {
                    const int row = wr * 128 + mi * 16 + quad * 4 + r;
                    float v = acc[mi][ni][r] + bv;
                    v = v > 0.f ? v : 0.f;
                    sC[row * 256 + n] = f2bf(v);
                }
        }
        __syncthreads();
        unsigned short* o16 = (unsigned short*)out;
        #pragma unroll
        for (int p = 0; p < 16; ++p) {
            const int idx = t + p * 512;             // ushort8 chunk 0..8191
            const int row = idx >> 5, ch = idx & 31;
            s8v c = *(const s8v*)&sC[row * 256 + ch * 8];
            if (MODE == 1) {
                const float rsv = rowsum[rowBase + row];
                const s8v xv = *(const s8v*)&xb[(size_t)(rowBase + row) * DDIM + colBase + ch * 8];
                #pragma unroll
                for (int j = 0; j < 8; ++j) {
                    float itv = bf2f((unsigned short)xv[j]) * rsv;
                    itv = itv > 0.f ? itv : 0.f;
                    c[j] = (short)f2bf(0.5f * (bf2f((unsigned short)c[j]) + itv));
                }
            }
            *(s8v*)&o16[(size_t)(rowBase + row) * DDIM + colBase + ch * 8] = c;
        }
    }
}

extern "C" void kernel_launch(void* const* d_in, const int* in_sizes, int n_in,
                              void* d_out, int out_size, void* d_ws, size_t ws_size,
                              hipStream_t stream) {
    const float* x  = (const float*)d_in[0];
    const float* Ws = (const float*)d_in[1];
    const float* bs = (const float*)d_in[2];
    const float* Wo = (const float*)d_in[3];
    const float* bo = (const float*)d_in[4];
    float* out = (float*)d_out;

    char* ws = (char*)d_ws;
    unsigned short* xb  = (unsigned short*)(ws);                 // 32 MB bf16 x
    unsigned short* h0  = (unsigned short*)(ws + 33554432);      // 32 MB
    unsigned short* h1  = (unsigned short*)(ws + 67108864);      // 32 MB
    unsigned short* wb  = (unsigned short*)(ws + 100663296);     // 10 MB weights bf16
    float*          rsm = (float*)(ws + 111149056);              // 64 KB rowsum

    prep_cvt_kernel<<<BROWS + 1280, 256, 0, stream>>>(x, Ws, Wo, xb, wb, rsm);

    const size_t WSZ = (size_t)DDIM * DDIM;
    dim3 g(BROWS / 256, DDIM / 256);
    gemm256<0><<<g, 512, 0, stream>>>(xb, wb,           bs,            h0, nullptr, nullptr);
    gemm256<0><<<g, 512, 0, stream>>>(h0, wb + 1 * WSZ, bs + 1 * DDIM, h1, nullptr, nullptr);
    gemm256<0><<<g, 512, 0, stream>>>(h1, wb + 2 * WSZ, bs + 2 * DDIM, h0, nullptr, nullptr);
    gemm256<1><<<g, 512, 0, stream>>>(h0, wb + 3 * WSZ, bs + 3 * DDIM, h1, xb, rsm);
    gemm256<2><<<g, 512, 0, stream>>>(h1, wb + 4 * WSZ, bo,            out, nullptr, nullptr);
}